// Round 4
// baseline (631.633 us; speedup 1.0000x reference)
//
#include <hip/hip_runtime.h>
#include <stdint.h>

typedef unsigned short u16;
typedef short bf16x8 __attribute__((ext_vector_type(8)));
typedef short bf16x4 __attribute__((ext_vector_type(4)));
typedef float f32x4 __attribute__((ext_vector_type(4)));
typedef u16 u16x8 __attribute__((ext_vector_type(8)));
typedef u16 u16x4 __attribute__((ext_vector_type(4)));

#define NHEADS 8
#define SEQ 1024
#define DM 512
#define DEPTH 64
#define BATCH 8
#define BK 32
#define LDSROW 40    // GEMM LDS row: 32 + 8 pad
#define PSTRIDE 1032 // attn P row: 1024 + 8 pad

__device__ __forceinline__ u16 f2bf(float f) {
    union { float f; unsigned u; } v; v.f = f;
    unsigned r = v.u + 0x7FFF + ((v.u >> 16) & 1);
    return (u16)(r >> 16);
}

template <typename T>
__device__ __forceinline__ void st_nt(T* p, T v) {
#if __has_builtin(__builtin_nontemporal_store)
    __builtin_nontemporal_store(v, p);
#else
    *p = v;
#endif
}
template <typename T>
__device__ __forceinline__ T ld_nt(const T* p) {
#if __has_builtin(__builtin_nontemporal_load)
    return __builtin_nontemporal_load(p);
#else
    return *p;
#endif
}

// ---------------------------------------------------------------- prep
__global__ void __launch_bounds__(256) transpose512(
    const float* __restrict__ w0, const float* __restrict__ w1,
    const float* __restrict__ w2, const float* __restrict__ w3,
    u16* __restrict__ wt)
{
    __shared__ float tile[32][33];
    const float* w = (blockIdx.z == 0) ? w0 : (blockIdx.z == 1) ? w1
                   : (blockIdx.z == 2) ? w2 : w3;
    u16* o = wt + (size_t)blockIdx.z * (DM * DM);
    int rb = blockIdx.y * 32, cb = blockIdx.x * 32;
    int tx = threadIdx.x, ty = threadIdx.y;  // 32 x 8
    #pragma unroll
    for (int k = 0; k < 32; k += 8)
        tile[ty + k][tx] = w[(size_t)(rb + ty + k) * DM + cb + tx];
    __syncthreads();
    #pragma unroll
    for (int k = 0; k < 32; k += 8)
        o[(size_t)(cb + ty + k) * DM + rb + tx] = f2bf(tile[tx][ty + k]);
}

// ---------------------------------------------------------------- GEMM core
// Reg-staged, double-buffered LDS GEMM. 128x128 tile, BK=32, 4 waves 2x2.
// AF32=1: A is f32, converted to bf16 during staging (fused conv).
template <int LAYOUT, int AF32>
__device__ __forceinline__ void gemm_tile2(
    const void* __restrict__ Asrc, const u16* __restrict__ wt,
    const float* __restrict__ bias, void* __restrict__ out_)
{
    __shared__ u16 Al[2][128 * LDSROW];
    __shared__ u16 Bl[2][128 * LDSROW];

    const int tid = threadIdx.x;
    const int wid = tid >> 6, lane = tid & 63;
    const int wm = wid >> 1, wn = wid & 1;
    const int lr = lane & 15, g = lane >> 4, lk = g * 8;
    const int mb = blockIdx.y * 128;
    const int nb = blockIdx.x * 128;
    const int r0 = tid >> 2;          // staging row 0..63
    const int c0 = (tid & 3) * 8;     // staging col chunk

    f32x4 fa0a, fa0b, fa1a, fa1b;
    u16x8 ua0, ua1, ub0, ub1;

    auto loadStage = [&](int ks) {
        if (AF32) {
            const float* A = (const float*)Asrc;
            fa0a = *(const f32x4*)(A + (size_t)(mb + r0) * DM + ks + c0);
            fa0b = *(const f32x4*)(A + (size_t)(mb + r0) * DM + ks + c0 + 4);
            fa1a = *(const f32x4*)(A + (size_t)(mb + 64 + r0) * DM + ks + c0);
            fa1b = *(const f32x4*)(A + (size_t)(mb + 64 + r0) * DM + ks + c0 + 4);
        } else {
            const u16* A = (const u16*)Asrc;
            ua0 = *(const u16x8*)(A + (size_t)(mb + r0) * DM + ks + c0);
            ua1 = *(const u16x8*)(A + (size_t)(mb + 64 + r0) * DM + ks + c0);
        }
        ub0 = *(const u16x8*)(wt + (size_t)(nb + r0) * DM + ks + c0);
        ub1 = *(const u16x8*)(wt + (size_t)(nb + 64 + r0) * DM + ks + c0);
    };
    auto writeStage = [&](int buf) {
        u16x8 w0, w1;
        if (AF32) {
            #pragma unroll
            for (int j = 0; j < 4; j++) {
                w0[j] = f2bf(fa0a[j]); w0[j + 4] = f2bf(fa0b[j]);
                w1[j] = f2bf(fa1a[j]); w1[j + 4] = f2bf(fa1b[j]);
            }
        } else { w0 = ua0; w1 = ua1; }
        *(u16x8*)(&Al[buf][r0 * LDSROW + c0]) = w0;
        *(u16x8*)(&Al[buf][(64 + r0) * LDSROW + c0]) = w1;
        *(u16x8*)(&Bl[buf][r0 * LDSROW + c0]) = ub0;
        *(u16x8*)(&Bl[buf][(64 + r0) * LDSROW + c0]) = ub1;
    };

    f32x4 acc[4][4];
    #pragma unroll
    for (int i = 0; i < 4; i++)
        #pragma unroll
        for (int j = 0; j < 4; j++) acc[i][j] = (f32x4)0.f;

    loadStage(0);
    for (int ks = 0, step = 0; ks < DM; ks += BK, step++) {
        const int buf = step & 1;
        writeStage(buf);
        if (ks + BK < DM) loadStage(ks + BK);  // prefetch survives barrier
        __syncthreads();

        bf16x8 af[4], bf4[4];
        #pragma unroll
        for (int mt = 0; mt < 4; mt++)
            af[mt] = *(const bf16x8*)(&Al[buf][(wm * 64 + mt * 16 + lr) * LDSROW + lk]);
        #pragma unroll
        for (int nt = 0; nt < 4; nt++)
            bf4[nt] = *(const bf16x8*)(&Bl[buf][(wn * 64 + nt * 16 + lr) * LDSROW + lk]);
        #pragma unroll
        for (int mt = 0; mt < 4; mt++)
            #pragma unroll
            for (int nt = 0; nt < 4; nt++) {
                if (LAYOUT == 1)
                    acc[mt][nt] = __builtin_amdgcn_mfma_f32_16x16x32_bf16(
                        bf4[nt], af[mt], acc[mt][nt], 0, 0, 0);
                else
                    acc[mt][nt] = __builtin_amdgcn_mfma_f32_16x16x32_bf16(
                        af[mt], bf4[nt], acc[mt][nt], 0, 0, 0);
            }
    }

    #pragma unroll
    for (int mt = 0; mt < 4; mt++) {
        #pragma unroll
        for (int nt = 0; nt < 4; nt++) {
            #pragma unroll
            for (int r = 0; r < 4; r++) {
                if (LAYOUT == 1) {
                    int m = mb + wm * 64 + mt * 16 + lr;
                    int n = nb + wn * 64 + nt * 16 + 4 * g + r;
                    float val = acc[mt][nt][r] + bias[n];
                    int b_ = m >> 10, s = m & 1023, h = n >> 6, d = n & 63;
                    st_nt(&((u16*)out_)[((size_t)((b_ * NHEADS + h) << 6) + d) * SEQ + s], f2bf(val));
                } else {
                    int n = nb + wn * 64 + nt * 16 + lr;
                    int m = mb + wm * 64 + mt * 16 + 4 * g + r;
                    float val = acc[mt][nt][r] + bias[n];
                    if (LAYOUT == 2) {
                        st_nt(&((float*)out_)[(size_t)m * DM + n], val);
                    } else {
                        int b_ = m >> 10, s = m & 1023, h = n >> 6, d = n & 63;
                        st_nt(&((u16*)out_)[(((size_t)(b_ * NHEADS + h) * SEQ + s) << 6) + d], f2bf(val));
                    }
                }
            }
        }
    }
}

__global__ void __launch_bounds__(256) qkv_proj(
    const float* __restrict__ q_in, const float* __restrict__ k_in,
    const float* __restrict__ v_in, const u16* __restrict__ wt_base,
    const float* __restrict__ bq, const float* __restrict__ bk,
    const float* __restrict__ bv,
    u16* __restrict__ Qb, u16* __restrict__ Kb, u16* __restrict__ VTb)
{
    int z = blockIdx.z;
    if (z == 0)      gemm_tile2<0, 1>(q_in, wt_base,               bq, Qb);
    else if (z == 1) gemm_tile2<0, 1>(k_in, wt_base + DM * DM,     bk, Kb);
    else             gemm_tile2<1, 1>(v_in, wt_base + 2 * DM * DM, bv, VTb);
}

__global__ void __launch_bounds__(256) out_proj(
    const u16* __restrict__ X, const u16* __restrict__ wto,
    const float* __restrict__ bo, float* __restrict__ out)
{
    gemm_tile2<2, 0>(X, wto, bo, out);
}

// ---------------------------------------------------------------- attention
// Round-1 phase structure (proven fastest) at 2x the wave count:
// 512 threads = 8 waves, each wave owns a 128-col k-stripe (acc[8] = 32 AGPR,
// half of r1 -> ~6 waves/SIMD feasible; LDS ~42KB -> 3 blocks/CU = 24 waves).
// Grid (8,64,8) natural: id%8 == h -> one head's K/V stays L2-resident per XCD.
// PV: wave (kh=wid>>2, dq=wid&3) computes partial X over k-half kh for
// d in [dq*16, dq*16+16); 8KB LDS combine.
__global__ void __launch_bounds__(512, 6) attn_kernel(
    const u16* __restrict__ Q, const u16* __restrict__ K,
    const u16* __restrict__ VT, const float* __restrict__ mask,
    const float* __restrict__ addw, float* __restrict__ attn_out,
    u16* __restrict__ X)
{
    __shared__ u16 Pl[16 * PSTRIDE];      // 33 KB
    __shared__ float Xr[2][16][64];       // 8 KB
    __shared__ float redm[8][16];
    __shared__ float reds[8][16];

    const int h = blockIdx.x, qt = blockIdx.y, b = blockIdx.z;
    const int tid = threadIdx.x, wid = tid >> 6, lane = tid & 63;
    const int lr = lane & 15, g = lane >> 4, lk = g * 8;
    const size_t head = (size_t)(b * NHEADS + h) * (SEQ * DEPTH);
    const u16* Qh = Q + head + (size_t)qt * 16 * DEPTH;
    const u16* Kh = K + head;
    const u16* Vh = VT + head;            // [64][1024] bf16
    const int wbase = wid << 7;           // wave's 128-col k-stripe

    // ---- phase 1: S = K @ Q^T (swapped): acc[nt][r] = S[q=lr][wbase+nt*16+4g+r]
    bf16x8 qf0 = *(const bf16x8*)(Qh + lr * DEPTH + lk);
    bf16x8 qf1 = *(const bf16x8*)(Qh + lr * DEPTH + 32 + lk);
    f32x4 acc[8];
    #pragma unroll
    for (int nt = 0; nt < 8; nt++) acc[nt] = (f32x4)0.f;
    #pragma unroll
    for (int nt = 0; nt < 8; nt++) {
        const u16* kp = Kh + (size_t)(wbase + (nt << 4) + lr) * DEPTH + lk;
        bf16x8 k0 = *(const bf16x8*)kp;
        bf16x8 k1 = *(const bf16x8*)(kp + 32);
        acc[nt] = __builtin_amdgcn_mfma_f32_16x16x32_bf16(k0, qf0, acc[nt], 0, 0, 0);
        acc[nt] = __builtin_amdgcn_mfma_f32_16x16x32_bf16(k1, qf1, acc[nt], 0, 0, 0);
    }

    // ---- scale + mask + per-lane max
    const float* mrow = mask + ((size_t)b << 10);
    float mx = -3.0e38f;
    #pragma unroll
    for (int nt = 0; nt < 8; nt++) {
        f32x4 mr = *(const f32x4*)(mrow + wbase + (nt << 4) + 4 * g);
        #pragma unroll
        for (int r = 0; r < 4; r++) {
            acc[nt][r] = acc[nt][r] * 0.125f + mr[r] * -1e9f;
            mx = fmaxf(mx, acc[nt][r]);
        }
    }
    mx = fmaxf(mx, __shfl_xor(mx, 16, 64));
    mx = fmaxf(mx, __shfl_xor(mx, 32, 64));
    if (lane < 16) redm[wid][lr] = mx;
    __syncthreads();
    float gm = redm[0][lr];
    #pragma unroll
    for (int w = 1; w < 8; w++) gm = fmaxf(gm, redm[w][lr]);

    // ---- exp + row sum
    float sm = 0.f;
    #pragma unroll
    for (int nt = 0; nt < 8; nt++)
        #pragma unroll
        for (int r = 0; r < 4; r++) {
            float pv = __expf(acc[nt][r] - gm);
            acc[nt][r] = pv;
            sm += pv;
        }
    sm += __shfl_xor(sm, 16, 64);
    sm += __shfl_xor(sm, 32, 64);
    if (lane < 16) reds[wid][lr] = sm;
    __syncthreads();
    float sv = reds[0][lr];
    #pragma unroll
    for (int w = 1; w < 8; w++) sv += reds[w][lr];
    float iv = 1.0f / sv;

    // ---- phase 2: addw * P -> nt attn store + P stash (stores decoupled)
    const int qglob = (qt << 4) + lr;
    const size_t awbase = ((size_t)((b << 10) + qglob)) << 10;
    const size_t aobase = ((size_t)(((b * NHEADS + h) << 10) + qglob)) << 10;
    #pragma unroll
    for (int nt = 0; nt < 8; nt++) {
        const int kk = wbase + (nt << 4) + 4 * g;
        f32x4 aw = ld_nt((const f32x4*)(addw + awbase + kk));
        f32x4 o;
        u16x4 pb;
        #pragma unroll
        for (int r = 0; r < 4; r++) {
            float v = acc[nt][r] * iv * aw[r];
            o[r] = v;
            pb[r] = f2bf(v);
        }
        st_nt((f32x4*)(attn_out + aobase + kk), o);
        *(u16x4*)(Pl + lr * PSTRIDE + kk) = pb;
    }
    __syncthreads();

    // ---- phase 3: X = P @ V; wave (kh, dq): k-half kh, d in [dq*16, dq*16+16)
    const int kh = wid >> 2, dq = wid & 3;
    f32x4 x = (f32x4)0.f;
    const u16* vrow = Vh + (size_t)((dq << 4) + lr) * SEQ;
    const int ks0 = kh << 9;
    for (int ks = ks0; ks < ks0 + 512; ks += 32) {
        bf16x8 a = *(const bf16x8*)(Pl + lr * PSTRIDE + ks + lk);
        bf16x8 bv = *(const bf16x8*)(vrow + ks + lk);
        x = __builtin_amdgcn_mfma_f32_16x16x32_bf16(a, bv, x, 0, 0, 0);
    }
    #pragma unroll
    for (int r = 0; r < 4; r++)
        Xr[kh][4 * g + r][(dq << 4) + lr] = x[r];
    __syncthreads();

    // final combine: each thread covers 2 (q,d) pairs
    #pragma unroll
    for (int rr = 0; rr < 2; rr++) {
        int q = 4 * g + (kh << 1) + rr;
        int d = (dq << 4) + lr;
        float s = Xr[0][q][d] + Xr[1][q][d];
        st_nt(&X[((size_t)((b << 10) + (qt << 4) + q)) * DM + (h << 6) + d], f2bf(s));
    }
}

// ---------------------------------------------------------------- launch
extern "C" void kernel_launch(void* const* d_in, const int* in_sizes, int n_in,
                              void* d_out, int out_size, void* d_ws, size_t ws_size,
                              hipStream_t stream)
{
    const float* q_in = (const float*)d_in[0];
    const float* k_in = (const float*)d_in[1];
    const float* v_in = (const float*)d_in[2];
    const float* mask = (const float*)d_in[3];
    const float* addw = (const float*)d_in[4];
    const float* wq = (const float*)d_in[5];
    const float* bq = (const float*)d_in[6];
    const float* wk = (const float*)d_in[7];
    const float* bk = (const float*)d_in[8];
    const float* wv = (const float*)d_in[9];
    const float* bv = (const float*)d_in[10];
    const float* wo = (const float*)d_in[11];
    const float* bo = (const float*)d_in[12];

    const size_t ACT = (size_t)BATCH * SEQ * DM;   // 4,194,304 elements

    u16* ws = (u16*)d_ws;
    u16* wt  = ws;                    // 4 * 512*512 bf16      (2 MB)
    u16* Qb  = wt + 4 * DM * DM;      // [B,H,S,D] bf16        (8 MB)
    u16* Kb  = Qb + ACT;              // [B,H,S,D] bf16        (8 MB)
    u16* VTb = Kb + ACT;              // [B,H,D,S] bf16        (8 MB)
    u16* Xb  = VTb + ACT;             // [B,S,DM]  bf16        (8 MB)

    float* out0 = (float*)d_out;                         // [B,S,512] f32
    float* attn_out = out0 + ACT;                        // [B,H,S,S] f32 (268 MB)

    transpose512<<<dim3(16, 16, 4), dim3(32, 8), 0, stream>>>(wq, wk, wv, wo, wt);
    qkv_proj<<<dim3(4, 64, 3), 256, 0, stream>>>(q_in, k_in, v_in, wt,
                                                 bq, bk, bv, Qb, Kb, VTb);
    attn_kernel<<<dim3(8, 64, 8), 512, 0, stream>>>(Qb, Kb, VTb, mask, addw,
                                                    attn_out, Xb);
    out_proj<<<dim3(4, 64, 1), 256, 0, stream>>>(Xb, wt + 3 * DM * DM, bo, out0);
}

// Round 7
// 567.679 us; speedup vs baseline: 1.1127x; 1.1127x over previous
//
#include <hip/hip_runtime.h>
#include <stdint.h>

typedef unsigned short u16;
typedef short bf16x8 __attribute__((ext_vector_type(8)));
typedef short bf16x4 __attribute__((ext_vector_type(4)));
typedef float f32x4 __attribute__((ext_vector_type(4)));
typedef u16 u16x8 __attribute__((ext_vector_type(8)));
typedef u16 u16x4 __attribute__((ext_vector_type(4)));

#define NHEADS 8
#define SEQ 1024
#define DM 512
#define DEPTH 64
#define BATCH 8
#define BK 32
#define LDSROW 40    // GEMM LDS row: 32 + 8 pad
#define PSTRIDE 1032 // attn P row: 1024 + 8 pad

__device__ __forceinline__ u16 f2bf(float f) {
    union { float f; unsigned u; } v; v.f = f;
    unsigned r = v.u + 0x7FFF + ((v.u >> 16) & 1);
    return (u16)(r >> 16);
}

// ---------------------------------------------------------------- prep
__global__ void __launch_bounds__(256) transpose512(
    const float* __restrict__ w0, const float* __restrict__ w1,
    const float* __restrict__ w2, const float* __restrict__ w3,
    u16* __restrict__ wt)
{
    __shared__ float tile[32][33];
    const float* w = (blockIdx.z == 0) ? w0 : (blockIdx.z == 1) ? w1
                   : (blockIdx.z == 2) ? w2 : w3;
    u16* o = wt + (size_t)blockIdx.z * (DM * DM);
    int rb = blockIdx.y * 32, cb = blockIdx.x * 32;
    int tx = threadIdx.x, ty = threadIdx.y;  // 32 x 8
    #pragma unroll
    for (int k = 0; k < 32; k += 8)
        tile[ty + k][tx] = w[(size_t)(rb + ty + k) * DM + cb + tx];
    __syncthreads();
    #pragma unroll
    for (int k = 0; k < 32; k += 8)
        o[(size_t)(cb + ty + k) * DM + rb + tx] = f2bf(tile[tx][ty + k]);
}

// ---------------------------------------------------------------- GEMM core
// Reg-staged, double-buffered LDS GEMM. 128x128 tile, BK=32, 4 waves 2x2.
// AF32=1: A is f32, converted to bf16 during staging (fused conv).
template <int LAYOUT, int AF32>
__device__ __forceinline__ void gemm_tile2(
    const void* __restrict__ Asrc, const u16* __restrict__ wt,
    const float* __restrict__ bias, void* __restrict__ out_)
{
    __shared__ u16 Al[2][128 * LDSROW];
    __shared__ u16 Bl[2][128 * LDSROW];

    const int tid = threadIdx.x;
    const int wid = tid >> 6, lane = tid & 63;
    const int wm = wid >> 1, wn = wid & 1;
    const int lr = lane & 15, g = lane >> 4, lk = g * 8;
    const int mb = blockIdx.y * 128;
    const int nb = blockIdx.x * 128;
    const int r0 = tid >> 2;          // staging row 0..63
    const int c0 = (tid & 3) * 8;     // staging col chunk

    f32x4 fa0a, fa0b, fa1a, fa1b;
    u16x8 ua0, ua1, ub0, ub1;

    auto loadStage = [&](int ks) {
        if (AF32) {
            const float* A = (const float*)Asrc;
            fa0a = *(const f32x4*)(A + (size_t)(mb + r0) * DM + ks + c0);
            fa0b = *(const f32x4*)(A + (size_t)(mb + r0) * DM + ks + c0 + 4);
            fa1a = *(const f32x4*)(A + (size_t)(mb + 64 + r0) * DM + ks + c0);
            fa1b = *(const f32x4*)(A + (size_t)(mb + 64 + r0) * DM + ks + c0 + 4);
        } else {
            const u16* A = (const u16*)Asrc;
            ua0 = *(const u16x8*)(A + (size_t)(mb + r0) * DM + ks + c0);
            ua1 = *(const u16x8*)(A + (size_t)(mb + 64 + r0) * DM + ks + c0);
        }
        ub0 = *(const u16x8*)(wt + (size_t)(nb + r0) * DM + ks + c0);
        ub1 = *(const u16x8*)(wt + (size_t)(nb + 64 + r0) * DM + ks + c0);
    };
    auto writeStage = [&](int buf) {
        u16x8 w0, w1;
        if (AF32) {
            #pragma unroll
            for (int j = 0; j < 4; j++) {
                w0[j] = f2bf(fa0a[j]); w0[j + 4] = f2bf(fa0b[j]);
                w1[j] = f2bf(fa1a[j]); w1[j + 4] = f2bf(fa1b[j]);
            }
        } else { w0 = ua0; w1 = ua1; }
        *(u16x8*)(&Al[buf][r0 * LDSROW + c0]) = w0;
        *(u16x8*)(&Al[buf][(64 + r0) * LDSROW + c0]) = w1;
        *(u16x8*)(&Bl[buf][r0 * LDSROW + c0]) = ub0;
        *(u16x8*)(&Bl[buf][(64 + r0) * LDSROW + c0]) = ub1;
    };

    f32x4 acc[4][4];
    #pragma unroll
    for (int i = 0; i < 4; i++)
        #pragma unroll
        for (int j = 0; j < 4; j++) acc[i][j] = (f32x4)0.f;

    loadStage(0);
    for (int ks = 0, step = 0; ks < DM; ks += BK, step++) {
        const int buf = step & 1;
        writeStage(buf);
        if (ks + BK < DM) loadStage(ks + BK);  // prefetch survives barrier
        __syncthreads();

        bf16x8 af[4], bf4[4];
        #pragma unroll
        for (int mt = 0; mt < 4; mt++)
            af[mt] = *(const bf16x8*)(&Al[buf][(wm * 64 + mt * 16 + lr) * LDSROW + lk]);
        #pragma unroll
        for (int nt = 0; nt < 4; nt++)
            bf4[nt] = *(const bf16x8*)(&Bl[buf][(wn * 64 + nt * 16 + lr) * LDSROW + lk]);
        #pragma unroll
        for (int mt = 0; mt < 4; mt++)
            #pragma unroll
            for (int nt = 0; nt < 4; nt++) {
                if (LAYOUT == 1)
                    acc[mt][nt] = __builtin_amdgcn_mfma_f32_16x16x32_bf16(
                        bf4[nt], af[mt], acc[mt][nt], 0, 0, 0);
                else
                    acc[mt][nt] = __builtin_amdgcn_mfma_f32_16x16x32_bf16(
                        af[mt], bf4[nt], acc[mt][nt], 0, 0, 0);
            }
    }

    #pragma unroll
    for (int mt = 0; mt < 4; mt++) {
        #pragma unroll
        for (int nt = 0; nt < 4; nt++) {
            #pragma unroll
            for (int r = 0; r < 4; r++) {
                if (LAYOUT == 1) {
                    int m = mb + wm * 64 + mt * 16 + lr;
                    int n = nb + wn * 64 + nt * 16 + 4 * g + r;
                    float val = acc[mt][nt][r] + bias[n];
                    int b_ = m >> 10, s = m & 1023, h = n >> 6, d = n & 63;
                    ((u16*)out_)[((size_t)((b_ * NHEADS + h) << 6) + d) * SEQ + s] = f2bf(val);
                } else {
                    int n = nb + wn * 64 + nt * 16 + lr;
                    int m = mb + wm * 64 + mt * 16 + 4 * g + r;
                    float val = acc[mt][nt][r] + bias[n];
                    if (LAYOUT == 2) {
                        ((float*)out_)[(size_t)m * DM + n] = val;
                    } else {
                        int b_ = m >> 10, s = m & 1023, h = n >> 6, d = n & 63;
                        ((u16*)out_)[(((size_t)(b_ * NHEADS + h) * SEQ + s) << 6) + d] = f2bf(val);
                    }
                }
            }
        }
    }
}

__global__ void __launch_bounds__(256) qkv_proj(
    const float* __restrict__ q_in, const float* __restrict__ k_in,
    const float* __restrict__ v_in, const u16* __restrict__ wt_base,
    const float* __restrict__ bq, const float* __restrict__ bk,
    const float* __restrict__ bv,
    u16* __restrict__ Qb, u16* __restrict__ Kb, u16* __restrict__ VTb)
{
    int z = blockIdx.z;
    if (z == 0)      gemm_tile2<0, 1>(q_in, wt_base,               bq, Qb);
    else if (z == 1) gemm_tile2<0, 1>(k_in, wt_base + DM * DM,     bk, Kb);
    else             gemm_tile2<1, 1>(v_in, wt_base + 2 * DM * DM, bv, VTb);
}

__global__ void __launch_bounds__(256) out_proj(
    const u16* __restrict__ X, const u16* __restrict__ wto,
    const float* __restrict__ bo, float* __restrict__ out)
{
    gemm_tile2<2, 0>(X, wto, bo, out);
}

// ---------------------------------------------------------------- attention
// 8 waves x 128-col k-stripes (r4 concurrency, 2.5 TB/s operating point)
// + r1's bijective XCD remap (all 8 h of one (b,qt) share id%8 -> same XCD,
// addw panel loaded once per XCD: FETCH ~104 MB proven) + PLAIN stores/loads
// (L2 merges the 64B half-line store chunks; nt hints caused 2x write amp).
__global__ void __launch_bounds__(512, 6) attn_kernel(
    const u16* __restrict__ Q, const u16* __restrict__ K,
    const u16* __restrict__ VT, const float* __restrict__ mask,
    const float* __restrict__ addw, float* __restrict__ attn_out,
    u16* __restrict__ X)
{
    __shared__ u16 Pl[16 * PSTRIDE];      // 33 KB
    __shared__ float Xr[2][16][64];       // 8 KB
    __shared__ float redm[8][16];
    __shared__ float reds[8][16];

    // bijective remap: id = c + 8*(h + 8*u), p = 8u + c = b*64 + qt
    const int id = blockIdx.x;
    const int c = id & 7, t = id >> 3;
    const int h = t & 7;
    const int p = ((t >> 3) << 3) | c;
    const int qt = p & 63, b = p >> 6;

    const int tid = threadIdx.x, wid = tid >> 6, lane = tid & 63;
    const int lr = lane & 15, g = lane >> 4, lk = g * 8;
    const size_t head = (size_t)(b * NHEADS + h) * (SEQ * DEPTH);
    const u16* Qh = Q + head + (size_t)qt * 16 * DEPTH;
    const u16* Kh = K + head;
    const u16* Vh = VT + head;            // [64][1024] bf16
    const int wbase = wid << 7;           // wave's 128-col k-stripe

    // ---- phase 1: S = K @ Q^T (swapped): acc[nt][r] = S[q=lr][wbase+nt*16+4g+r]
    bf16x8 qf0 = *(const bf16x8*)(Qh + lr * DEPTH + lk);
    bf16x8 qf1 = *(const bf16x8*)(Qh + lr * DEPTH + 32 + lk);
    f32x4 acc[8];
    #pragma unroll
    for (int nt = 0; nt < 8; nt++) acc[nt] = (f32x4)0.f;
    #pragma unroll
    for (int nt = 0; nt < 8; nt++) {
        const u16* kp = Kh + (size_t)(wbase + (nt << 4) + lr) * DEPTH + lk;
        bf16x8 k0 = *(const bf16x8*)kp;
        bf16x8 k1 = *(const bf16x8*)(kp + 32);
        acc[nt] = __builtin_amdgcn_mfma_f32_16x16x32_bf16(k0, qf0, acc[nt], 0, 0, 0);
        acc[nt] = __builtin_amdgcn_mfma_f32_16x16x32_bf16(k1, qf1, acc[nt], 0, 0, 0);
    }

    // ---- scale + mask + per-lane max
    const float* mrow = mask + ((size_t)b << 10);
    float mx = -3.0e38f;
    #pragma unroll
    for (int nt = 0; nt < 8; nt++) {
        f32x4 mr = *(const f32x4*)(mrow + wbase + (nt << 4) + 4 * g);
        #pragma unroll
        for (int r = 0; r < 4; r++) {
            acc[nt][r] = acc[nt][r] * 0.125f + mr[r] * -1e9f;
            mx = fmaxf(mx, acc[nt][r]);
        }
    }
    mx = fmaxf(mx, __shfl_xor(mx, 16, 64));
    mx = fmaxf(mx, __shfl_xor(mx, 32, 64));
    if (lane < 16) redm[wid][lr] = mx;
    __syncthreads();
    float gm = redm[0][lr];
    #pragma unroll
    for (int w = 1; w < 8; w++) gm = fmaxf(gm, redm[w][lr]);

    // ---- exp + row sum
    float sm = 0.f;
    #pragma unroll
    for (int nt = 0; nt < 8; nt++)
        #pragma unroll
        for (int r = 0; r < 4; r++) {
            float pv = __expf(acc[nt][r] - gm);
            acc[nt][r] = pv;
            sm += pv;
        }
    sm += __shfl_xor(sm, 16, 64);
    sm += __shfl_xor(sm, 32, 64);
    if (lane < 16) reds[wid][lr] = sm;
    __syncthreads();
    float sv = reds[0][lr];
    #pragma unroll
    for (int w = 1; w < 8; w++) sv += reds[w][lr];
    float iv = 1.0f / sv;

    // ---- phase 2: addw * P -> attn store + P stash
    const int qglob = (qt << 4) + lr;
    const size_t awbase = ((size_t)((b << 10) + qglob)) << 10;
    const size_t aobase = ((size_t)(((b * NHEADS + h) << 10) + qglob)) << 10;
    #pragma unroll
    for (int nt = 0; nt < 8; nt++) {
        const int kk = wbase + (nt << 4) + 4 * g;
        f32x4 aw = *(const f32x4*)(addw + awbase + kk);
        f32x4 o;
        u16x4 pb;
        #pragma unroll
        for (int r = 0; r < 4; r++) {
            float v = acc[nt][r] * iv * aw[r];
            o[r] = v;
            pb[r] = f2bf(v);
        }
        *(f32x4*)(attn_out + aobase + kk) = o;
        *(u16x4*)(Pl + lr * PSTRIDE + kk) = pb;
    }
    __syncthreads();

    // ---- phase 3: X = P @ V; wave (kh, dq): k-half kh, d in [dq*16, dq*16+16)
    const int kh = wid >> 2, dq = wid & 3;
    f32x4 x = (f32x4)0.f;
    const u16* vrow = Vh + (size_t)((dq << 4) + lr) * SEQ;
    const int ks0 = kh << 9;
    for (int ks = ks0; ks < ks0 + 512; ks += 32) {
        bf16x8 a = *(const bf16x8*)(Pl + lr * PSTRIDE + ks + lk);
        bf16x8 bv = *(const bf16x8*)(vrow + ks + lk);
        x = __builtin_amdgcn_mfma_f32_16x16x32_bf16(a, bv, x, 0, 0, 0);
    }
    #pragma unroll
    for (int r = 0; r < 4; r++)
        Xr[kh][4 * g + r][(dq << 4) + lr] = x[r];
    __syncthreads();

    // final combine: each thread covers 2 (q,d) pairs
    #pragma unroll
    for (int rr = 0; rr < 2; rr++) {
        int q = 4 * g + (kh << 1) + rr;
        int d = (dq << 4) + lr;
        float s = Xr[0][q][d] + Xr[1][q][d];
        X[((size_t)((b << 10) + (qt << 4) + q)) * DM + (h << 6) + d] = f2bf(s);
    }
}

// ---------------------------------------------------------------- launch
extern "C" void kernel_launch(void* const* d_in, const int* in_sizes, int n_in,
                              void* d_out, int out_size, void* d_ws, size_t ws_size,
                              hipStream_t stream)
{
    const float* q_in = (const float*)d_in[0];
    const float* k_in = (const float*)d_in[1];
    const float* v_in = (const float*)d_in[2];
    const float* mask = (const float*)d_in[3];
    const float* addw = (const float*)d_in[4];
    const float* wq = (const float*)d_in[5];
    const float* bq = (const float*)d_in[6];
    const float* wk = (const float*)d_in[7];
    const float* bk = (const float*)d_in[8];
    const float* wv = (const float*)d_in[9];
    const float* bv = (const float*)d_in[10];
    const float* wo = (const float*)d_in[11];
    const float* bo = (const float*)d_in[12];

    const size_t ACT = (size_t)BATCH * SEQ * DM;   // 4,194,304 elements

    u16* ws = (u16*)d_ws;
    u16* wt  = ws;                    // 4 * 512*512 bf16      (2 MB)
    u16* Qb  = wt + 4 * DM * DM;      // [B,H,S,D] bf16        (8 MB)
    u16* Kb  = Qb + ACT;              // [B,H,S,D] bf16        (8 MB)
    u16* VTb = Kb + ACT;              // [B,H,D,S] bf16        (8 MB)
    u16* Xb  = VTb + ACT;             // [B,S,DM]  bf16        (8 MB)

    float* out0 = (float*)d_out;                         // [B,S,512] f32
    float* attn_out = out0 + ACT;                        // [B,H,S,S] f32 (268 MB)

    transpose512<<<dim3(16, 16, 4), dim3(32, 8), 0, stream>>>(wq, wk, wv, wo, wt);
    qkv_proj<<<dim3(4, 64, 3), 256, 0, stream>>>(q_in, k_in, v_in, wt,
                                                 bq, bk, bv, Qb, Kb, VTb);
    attn_kernel<<<dim3(4096), 512, 0, stream>>>(Qb, Kb, VTb, mask, addw,
                                                attn_out, Xb);
    out_proj<<<dim3(4, 64, 1), 256, 0, stream>>>(Xb, wt + 3 * DM * DM, bo, out0);
}

// Round 8
// 553.608 us; speedup vs baseline: 1.1409x; 1.0254x over previous
//
#include <hip/hip_runtime.h>
#include <stdint.h>

typedef unsigned short u16;
typedef short bf16x8 __attribute__((ext_vector_type(8)));
typedef short bf16x4 __attribute__((ext_vector_type(4)));
typedef float f32x4 __attribute__((ext_vector_type(4)));
typedef u16 u16x8 __attribute__((ext_vector_type(8)));
typedef u16 u16x4 __attribute__((ext_vector_type(4)));

#define NHEADS 8
#define SEQ 1024
#define DM 512
#define DEPTH 64
#define BATCH 8
#define BK 32
#define LDSROW 40    // GEMM LDS row: 32 + 8 pad
#define PSTRIDE 1032 // attn P row: 1024 + 8 pad

__device__ __forceinline__ u16 f2bf(float f) {
    union { float f; unsigned u; } v; v.f = f;
    unsigned r = v.u + 0x7FFF + ((v.u >> 16) & 1);
    return (u16)(r >> 16);
}

// ---------------------------------------------------------------- prep
__global__ void __launch_bounds__(256) transpose512(
    const float* __restrict__ w0, const float* __restrict__ w1,
    const float* __restrict__ w2, const float* __restrict__ w3,
    u16* __restrict__ wt)
{
    __shared__ float tile[32][33];
    const float* w = (blockIdx.z == 0) ? w0 : (blockIdx.z == 1) ? w1
                   : (blockIdx.z == 2) ? w2 : w3;
    u16* o = wt + (size_t)blockIdx.z * (DM * DM);
    int rb = blockIdx.y * 32, cb = blockIdx.x * 32;
    int tx = threadIdx.x, ty = threadIdx.y;  // 32 x 8
    #pragma unroll
    for (int k = 0; k < 32; k += 8)
        tile[ty + k][tx] = w[(size_t)(rb + ty + k) * DM + cb + tx];
    __syncthreads();
    #pragma unroll
    for (int k = 0; k < 32; k += 8)
        o[(size_t)(cb + ty + k) * DM + rb + tx] = f2bf(tile[tx][ty + k]);
}

// ---------------------------------------------------------------- GEMM core
// Reg-staged, double-buffered LDS GEMM. 128x128 tile, BK=32, 4 waves 2x2.
// AF32=1: A is f32, converted to bf16 during staging (fused conv).
template <int LAYOUT, int AF32>
__device__ __forceinline__ void gemm_tile2(
    const void* __restrict__ Asrc, const u16* __restrict__ wt,
    const float* __restrict__ bias, void* __restrict__ out_)
{
    __shared__ u16 Al[2][128 * LDSROW];
    __shared__ u16 Bl[2][128 * LDSROW];

    const int tid = threadIdx.x;
    const int wid = tid >> 6, lane = tid & 63;
    const int wm = wid >> 1, wn = wid & 1;
    const int lr = lane & 15, g = lane >> 4, lk = g * 8;
    const int mb = blockIdx.y * 128;
    const int nb = blockIdx.x * 128;
    const int r0 = tid >> 2;          // staging row 0..63
    const int c0 = (tid & 3) * 8;     // staging col chunk

    f32x4 fa0a, fa0b, fa1a, fa1b;
    u16x8 ua0, ua1, ub0, ub1;

    auto loadStage = [&](int ks) {
        if (AF32) {
            const float* A = (const float*)Asrc;
            fa0a = *(const f32x4*)(A + (size_t)(mb + r0) * DM + ks + c0);
            fa0b = *(const f32x4*)(A + (size_t)(mb + r0) * DM + ks + c0 + 4);
            fa1a = *(const f32x4*)(A + (size_t)(mb + 64 + r0) * DM + ks + c0);
            fa1b = *(const f32x4*)(A + (size_t)(mb + 64 + r0) * DM + ks + c0 + 4);
        } else {
            const u16* A = (const u16*)Asrc;
            ua0 = *(const u16x8*)(A + (size_t)(mb + r0) * DM + ks + c0);
            ua1 = *(const u16x8*)(A + (size_t)(mb + 64 + r0) * DM + ks + c0);
        }
        ub0 = *(const u16x8*)(wt + (size_t)(nb + r0) * DM + ks + c0);
        ub1 = *(const u16x8*)(wt + (size_t)(nb + 64 + r0) * DM + ks + c0);
    };
    auto writeStage = [&](int buf) {
        u16x8 w0, w1;
        if (AF32) {
            #pragma unroll
            for (int j = 0; j < 4; j++) {
                w0[j] = f2bf(fa0a[j]); w0[j + 4] = f2bf(fa0b[j]);
                w1[j] = f2bf(fa1a[j]); w1[j + 4] = f2bf(fa1b[j]);
            }
        } else { w0 = ua0; w1 = ua1; }
        *(u16x8*)(&Al[buf][r0 * LDSROW + c0]) = w0;
        *(u16x8*)(&Al[buf][(64 + r0) * LDSROW + c0]) = w1;
        *(u16x8*)(&Bl[buf][r0 * LDSROW + c0]) = ub0;
        *(u16x8*)(&Bl[buf][(64 + r0) * LDSROW + c0]) = ub1;
    };

    f32x4 acc[4][4];
    #pragma unroll
    for (int i = 0; i < 4; i++)
        #pragma unroll
        for (int j = 0; j < 4; j++) acc[i][j] = (f32x4)0.f;

    loadStage(0);
    for (int ks = 0, step = 0; ks < DM; ks += BK, step++) {
        const int buf = step & 1;
        writeStage(buf);
        if (ks + BK < DM) loadStage(ks + BK);  // prefetch survives barrier
        __syncthreads();

        bf16x8 af[4], bf4[4];
        #pragma unroll
        for (int mt = 0; mt < 4; mt++)
            af[mt] = *(const bf16x8*)(&Al[buf][(wm * 64 + mt * 16 + lr) * LDSROW + lk]);
        #pragma unroll
        for (int nt = 0; nt < 4; nt++)
            bf4[nt] = *(const bf16x8*)(&Bl[buf][(wn * 64 + nt * 16 + lr) * LDSROW + lk]);
        #pragma unroll
        for (int mt = 0; mt < 4; mt++)
            #pragma unroll
            for (int nt = 0; nt < 4; nt++) {
                if (LAYOUT == 1)
                    acc[mt][nt] = __builtin_amdgcn_mfma_f32_16x16x32_bf16(
                        bf4[nt], af[mt], acc[mt][nt], 0, 0, 0);
                else
                    acc[mt][nt] = __builtin_amdgcn_mfma_f32_16x16x32_bf16(
                        af[mt], bf4[nt], acc[mt][nt], 0, 0, 0);
            }
    }

    #pragma unroll
    for (int mt = 0; mt < 4; mt++) {
        #pragma unroll
        for (int nt = 0; nt < 4; nt++) {
            #pragma unroll
            for (int r = 0; r < 4; r++) {
                if (LAYOUT == 1) {
                    int m = mb + wm * 64 + mt * 16 + lr;
                    int n = nb + wn * 64 + nt * 16 + 4 * g + r;
                    float val = acc[mt][nt][r] + bias[n];
                    int b_ = m >> 10, s = m & 1023, h = n >> 6, d = n & 63;
                    ((u16*)out_)[((size_t)((b_ * NHEADS + h) << 6) + d) * SEQ + s] = f2bf(val);
                } else {
                    int n = nb + wn * 64 + nt * 16 + lr;
                    int m = mb + wm * 64 + mt * 16 + 4 * g + r;
                    float val = acc[mt][nt][r] + bias[n];
                    if (LAYOUT == 2) {
                        ((float*)out_)[(size_t)m * DM + n] = val;
                    } else {
                        int b_ = m >> 10, s = m & 1023, h = n >> 6, d = n & 63;
                        ((u16*)out_)[(((size_t)(b_ * NHEADS + h) * SEQ + s) << 6) + d] = f2bf(val);
                    }
                }
            }
        }
    }
}

__global__ void __launch_bounds__(256) qkv_proj(
    const float* __restrict__ q_in, const float* __restrict__ k_in,
    const float* __restrict__ v_in, const u16* __restrict__ wt_base,
    const float* __restrict__ bq, const float* __restrict__ bk,
    const float* __restrict__ bv,
    u16* __restrict__ Qb, u16* __restrict__ Kb, u16* __restrict__ VTb)
{
    int z = blockIdx.z;
    if (z == 0)      gemm_tile2<0, 1>(q_in, wt_base,               bq, Qb);
    else if (z == 1) gemm_tile2<0, 1>(k_in, wt_base + DM * DM,     bk, Kb);
    else             gemm_tile2<1, 1>(v_in, wt_base + 2 * DM * DM, bv, VTb);
}

__global__ void __launch_bounds__(256) out_proj(
    const u16* __restrict__ X, const u16* __restrict__ wto,
    const float* __restrict__ bo, float* __restrict__ out)
{
    gemm_tile2<2, 0>(X, wto, bo, out);
}

// ---------------------------------------------------------------- attention
// 8 waves x 128-col k-stripes, bijective XCD remap (addw-affine), plain
// stores. NEW (r8): __launch_bounds__(512,4) -> 128-VGPR budget, and explicit
// depth-4 software prefetch in every memory phase (K, addw, P/V). r7's VGPR=40
// allocation serialized every load->use chain; this buys per-wave MLP.
// X store: one full 128B line per store (wave w -> rows 2w/2w+1, d=lane).
__global__ void __launch_bounds__(512, 4) attn_kernel(
    const u16* __restrict__ Q, const u16* __restrict__ K,
    const u16* __restrict__ VT, const float* __restrict__ mask,
    const float* __restrict__ addw, float* __restrict__ attn_out,
    u16* __restrict__ X)
{
    __shared__ u16 Pl[16 * PSTRIDE];      // 33 KB
    __shared__ float Xr[2][16][64];       // 8 KB
    __shared__ float redm[8][16];
    __shared__ float reds[8][16];

    // bijective remap: id = c + 8*(h + 8*u), p = 8u + c = b*64 + qt
    const int id = blockIdx.x;
    const int c = id & 7, t = id >> 3;
    const int h = t & 7;
    const int p = ((t >> 3) << 3) | c;
    const int qt = p & 63, b = p >> 6;

    const int tid = threadIdx.x, wid = tid >> 6, lane = tid & 63;
    const int lr = lane & 15, g = lane >> 4, lk = g * 8;
    const size_t head = (size_t)(b * NHEADS + h) * (SEQ * DEPTH);
    const u16* Qh = Q + head + (size_t)qt * 16 * DEPTH;
    const u16* Kh = K + head;
    const u16* Vh = VT + head;            // [64][1024] bf16
    const int wbase = wid << 7;           // wave's 128-col k-stripe

    // ---- phase 1: S = K @ Q^T (swapped), depth-4 K prefetch
    bf16x8 qf0 = *(const bf16x8*)(Qh + lr * DEPTH + lk);
    bf16x8 qf1 = *(const bf16x8*)(Qh + lr * DEPTH + 32 + lk);
    f32x4 acc[8];
    #pragma unroll
    for (int nt = 0; nt < 8; nt++) acc[nt] = (f32x4)0.f;

    bf16x8 k0v[4], k1v[4];
    #pragma unroll
    for (int i = 0; i < 4; i++) {
        const u16* kp = Kh + (size_t)(wbase + (i << 4) + lr) * DEPTH + lk;
        k0v[i] = *(const bf16x8*)kp;
        k1v[i] = *(const bf16x8*)(kp + 32);
    }
    #pragma unroll
    for (int nt = 0; nt < 8; nt++) {
        bf16x8 c0 = k0v[nt & 3], c1 = k1v[nt & 3];
        if (nt + 4 < 8) {
            const u16* kp = Kh + (size_t)(wbase + ((nt + 4) << 4) + lr) * DEPTH + lk;
            k0v[nt & 3] = *(const bf16x8*)kp;
            k1v[nt & 3] = *(const bf16x8*)(kp + 32);
        }
        acc[nt] = __builtin_amdgcn_mfma_f32_16x16x32_bf16(c0, qf0, acc[nt], 0, 0, 0);
        acc[nt] = __builtin_amdgcn_mfma_f32_16x16x32_bf16(c1, qf1, acc[nt], 0, 0, 0);
    }

    // ---- scale + mask + per-lane max (mask batched first)
    const float* mrow = mask + ((size_t)b << 10);
    f32x4 mrv[8];
    #pragma unroll
    for (int nt = 0; nt < 8; nt++)
        mrv[nt] = *(const f32x4*)(mrow + wbase + (nt << 4) + 4 * g);
    float mx = -3.0e38f;
    #pragma unroll
    for (int nt = 0; nt < 8; nt++)
        #pragma unroll
        for (int r = 0; r < 4; r++) {
            acc[nt][r] = acc[nt][r] * 0.125f + mrv[nt][r] * -1e9f;
            mx = fmaxf(mx, acc[nt][r]);
        }
    mx = fmaxf(mx, __shfl_xor(mx, 16, 64));
    mx = fmaxf(mx, __shfl_xor(mx, 32, 64));
    if (lane < 16) redm[wid][lr] = mx;
    __syncthreads();
    float gm = redm[0][lr];
    #pragma unroll
    for (int w = 1; w < 8; w++) gm = fmaxf(gm, redm[w][lr]);

    // ---- exp + row sum
    float sm = 0.f;
    #pragma unroll
    for (int nt = 0; nt < 8; nt++)
        #pragma unroll
        for (int r = 0; r < 4; r++) {
            float pv = __expf(acc[nt][r] - gm);
            acc[nt][r] = pv;
            sm += pv;
        }
    sm += __shfl_xor(sm, 16, 64);
    sm += __shfl_xor(sm, 32, 64);
    if (lane < 16) reds[wid][lr] = sm;
    __syncthreads();
    float sv = reds[0][lr];
    #pragma unroll
    for (int w = 1; w < 8; w++) sv += reds[w][lr];
    float iv = 1.0f / sv;

    // ---- phase 2: addw loads batched (8 in flight), then compute+store
    const int qglob = (qt << 4) + lr;
    const size_t awbase = ((size_t)((b << 10) + qglob)) << 10;
    const size_t aobase = ((size_t)(((b * NHEADS + h) << 10) + qglob)) << 10;
    f32x4 awv[8];
    #pragma unroll
    for (int nt = 0; nt < 8; nt++)
        awv[nt] = *(const f32x4*)(addw + awbase + wbase + (nt << 4) + 4 * g);
    #pragma unroll
    for (int nt = 0; nt < 8; nt++) {
        const int kk = wbase + (nt << 4) + 4 * g;
        f32x4 o;
        u16x4 pb;
        #pragma unroll
        for (int r = 0; r < 4; r++) {
            float v = acc[nt][r] * iv * awv[nt][r];
            o[r] = v;
            pb[r] = f2bf(v);
        }
        *(f32x4*)(attn_out + aobase + kk) = o;
        *(u16x4*)(Pl + lr * PSTRIDE + kk) = pb;
    }
    __syncthreads();

    // ---- phase 3: X = P @ V, depth-4 prefetch on both P (LDS) and V (global)
    const int kh = wid >> 2, dq = wid & 3;
    f32x4 x = (f32x4)0.f;
    const u16* vrow = Vh + (size_t)((dq << 4) + lr) * SEQ;
    const int ks0 = kh << 9;

    bf16x8 pv4[4], vv4[4];
    #pragma unroll
    for (int i = 0; i < 4; i++) {
        pv4[i] = *(const bf16x8*)(Pl + lr * PSTRIDE + ks0 + i * 32 + lk);
        vv4[i] = *(const bf16x8*)(vrow + ks0 + i * 32 + lk);
    }
    #pragma unroll
    for (int t2 = 0; t2 < 16; t2++) {
        bf16x8 a = pv4[t2 & 3], bv = vv4[t2 & 3];
        if (t2 + 4 < 16) {
            pv4[t2 & 3] = *(const bf16x8*)(Pl + lr * PSTRIDE + ks0 + (t2 + 4) * 32 + lk);
            vv4[t2 & 3] = *(const bf16x8*)(vrow + ks0 + (t2 + 4) * 32 + lk);
        }
        x = __builtin_amdgcn_mfma_f32_16x16x32_bf16(a, bv, x, 0, 0, 0);
    }
    #pragma unroll
    for (int r = 0; r < 4; r++)
        Xr[kh][4 * g + r][(dq << 4) + lr] = x[r];
    __syncthreads();

    // final combine: wave w -> q rows {2w, 2w+1}, d = lane -> full 128B lines
    #pragma unroll
    for (int rr = 0; rr < 2; rr++) {
        int q = (wid << 1) + rr;
        float s = Xr[0][q][lane] + Xr[1][q][lane];
        X[((size_t)((b << 10) + (qt << 4) + q)) * DM + (h << 6) + lane] = f2bf(s);
    }
}

// ---------------------------------------------------------------- launch
extern "C" void kernel_launch(void* const* d_in, const int* in_sizes, int n_in,
                              void* d_out, int out_size, void* d_ws, size_t ws_size,
                              hipStream_t stream)
{
    const float* q_in = (const float*)d_in[0];
    const float* k_in = (const float*)d_in[1];
    const float* v_in = (const float*)d_in[2];
    const float* mask = (const float*)d_in[3];
    const float* addw = (const float*)d_in[4];
    const float* wq = (const float*)d_in[5];
    const float* bq = (const float*)d_in[6];
    const float* wk = (const float*)d_in[7];
    const float* bk = (const float*)d_in[8];
    const float* wv = (const float*)d_in[9];
    const float* bv = (const float*)d_in[10];
    const float* wo = (const float*)d_in[11];
    const float* bo = (const float*)d_in[12];

    const size_t ACT = (size_t)BATCH * SEQ * DM;   // 4,194,304 elements

    u16* ws = (u16*)d_ws;
    u16* wt  = ws;                    // 4 * 512*512 bf16      (2 MB)
    u16* Qb  = wt + 4 * DM * DM;      // [B,H,S,D] bf16        (8 MB)
    u16* Kb  = Qb + ACT;              // [B,H,S,D] bf16        (8 MB)
    u16* VTb = Kb + ACT;              // [B,H,D,S] bf16        (8 MB)
    u16* Xb  = VTb + ACT;             // [B,S,DM]  bf16        (8 MB)

    float* out0 = (float*)d_out;                         // [B,S,512] f32
    float* attn_out = out0 + ACT;                        // [B,H,S,S] f32 (268 MB)

    transpose512<<<dim3(16, 16, 4), dim3(32, 8), 0, stream>>>(wq, wk, wv, wo, wt);
    qkv_proj<<<dim3(4, 64, 3), 256, 0, stream>>>(q_in, k_in, v_in, wt,
                                                 bq, bk, bv, Qb, Kb, VTb);
    attn_kernel<<<dim3(4096), 512, 0, stream>>>(Qb, Kb, VTb, mask, addw,
                                                attn_out, Xb);
    out_proj<<<dim3(4, 64, 1), 256, 0, stream>>>(Xb, wt + 3 * DM * DM, bo, out0);
}